// Round 15
// baseline (80.568 us; speedup 1.0000x reference)
//
#include <hip/hip_runtime.h>
#include <math.h>

#define B_TOT   1024
#define L_SEQ   200
#define DIM     64
#define VOCAB   100001
#define NEG_BIG (-1e15f)
#define SEQ_ST16 66                     // bf16 row stride: 132 B -> 2-way (free) on both write & read
#define LOG2E   1.4426950408889634f
#define EB_SLACK_ROWS 512               // prefetch overrun slack (values never used)

typedef __bf16 bf16x8 __attribute__((ext_vector_type(8)));
typedef float  f32x4  __attribute__((ext_vector_type(4)));

// raw v_exp_f32 (exp2): inputs are bounded here, denormal guard unneeded
static __device__ __forceinline__ float fast_exp2(float x) {
    return __builtin_amdgcn_exp2f(x);
}

// ---------------------------------------------------------------------------
// Kernel A: attention pooling + tail-fused convert(E->bf16).  (R11 version)
// ---------------------------------------------------------------------------
__global__ __launch_bounds__(256) void pool_kernel(
    const int*   __restrict__ log_seqs,
    const float* __restrict__ item_emb,
    const float* __restrict__ attn_key,
    const float* __restrict__ pos_emb,
    float*       __restrict__ Q,
    __bf16*      __restrict__ Qb,
    __bf16*      __restrict__ Eb)
{
    const int b    = blockIdx.x;
    const int t    = threadIdx.x;
    const int wave = t >> 6;
    const int lane = t & 63;

    __shared__ unsigned short s_seq16[L_SEQ][SEQ_ST16];  // 26,400 B
    __shared__ float s_attn[L_SEQ];
    __shared__ float s_red[4];
    __shared__ float s_q[4][DIM];

    // ---- phase 1: seq row -> LDS (bf16), sim[l] ---------------------------
    float sim = -INFINITY;
    if (t < L_SEQ) {
        const int id = log_seqs[(long)b * L_SEQ + t];
        if (id == 0) {
            sim = NEG_BIG;
            const ushort2 z = make_ushort2(0, 0);
            #pragma unroll
            for (int i = 0; i < DIM / 2; ++i)
                *(ushort2*)&s_seq16[t][2 * i] = z;
        } else {
            float acc = 0.f;
            const float4* e4 = (const float4*)(item_emb + (long)id * DIM);
            const float4* p4 = (const float4*)(pos_emb + t * DIM);
            #pragma unroll
            for (int i = 0; i < DIM / 4; ++i) {
                const float4 e = e4[i];
                const float4 p = p4[i];
                float4 f;
                f.x = fmaf(8.f, e.x, p.x);
                f.y = fmaf(8.f, e.y, p.y);
                f.z = fmaf(8.f, e.z, p.z);
                f.w = fmaf(8.f, e.w, p.w);
                const __bf16 h0 = (__bf16)f.x, h1 = (__bf16)f.y;
                const __bf16 h2 = (__bf16)f.z, h3 = (__bf16)f.w;
                ushort2 u0, u1;
                u0.x = __builtin_bit_cast(unsigned short, h0);
                u0.y = __builtin_bit_cast(unsigned short, h1);
                u1.x = __builtin_bit_cast(unsigned short, h2);
                u1.y = __builtin_bit_cast(unsigned short, h3);
                *(ushort2*)&s_seq16[t][4 * i]     = u0;
                *(ushort2*)&s_seq16[t][4 * i + 2] = u1;
                // attn_key reads are thread-uniform -> scalar loads
                acc += f.x * attn_key[4*i+0] + f.y * attn_key[4*i+1]
                     + f.z * attn_key[4*i+2] + f.w * attn_key[4*i+3];
            }
            sim = acc;
        }
    }

    // ---- phase 2: block softmax over l -------------------------------------
    float m = sim;
    #pragma unroll
    for (int off = 32; off > 0; off >>= 1) m = fmaxf(m, __shfl_xor(m, off));
    if (lane == 0) s_red[wave] = m;
    __syncthreads();
    m = fmaxf(fmaxf(s_red[0], s_red[1]), fmaxf(s_red[2], s_red[3]));
    __syncthreads();                             // all waves read s_red

    float p = (t < L_SEQ) ? __expf(sim - m) : 0.f;
    if (t < L_SEQ) s_attn[t] = p;
    float ls = p;
    #pragma unroll
    for (int off = 32; off > 0; off >>= 1) ls += __shfl_xor(ls, off);
    if (lane == 0) s_red[wave] = ls;
    __syncthreads();
    const float inv = 1.0f / (s_red[0] + s_red[1] + s_red[2] + s_red[3]);

    // ---- phase 3: Q accumulation from LDS, L split across waves ------------
    float q = 0.f;
    const int l0 = wave * (L_SEQ / 4);
    #pragma unroll 2
    for (int l = l0; l < l0 + (L_SEQ / 4); ++l) {
        const unsigned int ui = (unsigned int)s_seq16[l][lane] << 16;
        q = fmaf(s_attn[l], __builtin_bit_cast(float, ui), q);
    }
    s_q[wave][lane] = q;
    __syncthreads();

    if (t < DIM) {
        const float qq = (s_q[0][t] + s_q[1][t] + s_q[2][t] + s_q[3][t]) * inv;
        Q[b * DIM + t]  = qq;
        Qb[b * DIM + t] = (__bf16)(qq * LOG2E);  // exp2-domain for logits kernel
    }

    // ---- tail: convert slice of item_emb -> bf16 ---------------------------
    {
        const long n8 = ((long)VOCAB * DIM) / 8;             // 800,008 groups
        for (long g = (long)b * 256 + t; g < n8; g += (long)gridDim.x * 256) {
            const long i = g * 8;
            const float4 f0 = ((const float4*)(item_emb + i))[0];
            const float4 f1 = ((const float4*)(item_emb + i))[1];
            bf16x8 o;
            o[0] = (__bf16)f0.x; o[1] = (__bf16)f0.y; o[2] = (__bf16)f0.z; o[3] = (__bf16)f0.w;
            o[4] = (__bf16)f1.x; o[5] = (__bf16)f1.y; o[6] = (__bf16)f1.z; o[7] = (__bf16)f1.w;
            *(bf16x8*)(Eb + i) = o;
        }
    }
}

// ---------------------------------------------------------------------------
// Kernel B: bf16 MFMA logits GEMM + exp2-sum partials.
// Same per-wave work as R8 (8 b-tiles reuse, a[8][2], stride-4 vtile walk,
// depth-2 prefetch, incremental unclamped pointers w/ slack) but ONE WAVE
// PER BLOCK: 64-thread blocks, grid = NBG*NC*4 = 4096.  No LDS, no barriers,
// wave = scheduling quantum -> residency gated by VGPR only, no block-tail.
// Each wave writes its own partials slot; finalize sums NC*4 = 512/row.
// Tail vtile masks via valid?:0.  XCD decode: chunk == xcd (mod 8).
// ---------------------------------------------------------------------------
#define NC        128                   // vocab chunks
#define NBG       8                     // batch groups (1024/128)
#define VT_TOTAL  6251                  // ceil(100001/16)
#define VT_FULL   6250
#define VT_PER    49                    // ceil(VT_TOTAL/NC)

__global__ __launch_bounds__(64) void logits_mfma(
    const __bf16* __restrict__ Eb,      // [VOCAB+slack][64]
    const __bf16* __restrict__ Qb,      // [1024][64], exp2-domain
    float*        __restrict__ partials) // [NC*4][1024]
{
    const int bid   = blockIdx.x;                 // 0..4095
    const int xcd   = bid & 7;          // HW round-robins blockIdx across XCDs
    const int sub   = bid >> 3;         // 0..511 within this XCD
    const int wslot = sub & 3;
    const int bg    = (sub >> 2) & 7;
    const int chunk = xcd + 8 * (sub >> 5);       // chunks == xcd (mod 8)
    const int lane  = threadIdx.x;
    const int r16   = lane & 15;
    const int hi    = lane >> 4;

    bf16x8 a[8][2];
    #pragma unroll
    for (int t = 0; t < 8; ++t)
        #pragma unroll
        for (int s = 0; s < 2; ++s)
            a[t][s] = *(const bf16x8*)(Qb + ((bg*128 + t*16 + r16) * DIM) + s*32 + hi*8);

    const int vt0    = chunk * VT_PER;
    const int vt_end = min(vt0 + VT_PER, VT_TOTAL);
    int vt = vt0 + wslot;

    float ssum[8][4];
    #pragma unroll
    for (int t = 0; t < 8; ++t)
        #pragma unroll
        for (int r = 0; r < 4; ++r) ssum[t][r] = 0.f;

    #define DO_TILE(c0, c1, v) do {                                           \
        if ((v) < VT_FULL) {                                                  \
            _Pragma("unroll")                                                 \
            for (int t = 0; t < 8; ++t) {                                     \
                f32x4 acc = {0.f, 0.f, 0.f, 0.f};                             \
                acc = __builtin_amdgcn_mfma_f32_16x16x32_bf16(a[t][0], c0, acc, 0, 0, 0); \
                acc = __builtin_amdgcn_mfma_f32_16x16x32_bf16(a[t][1], c1, acc, 0, 0, 0); \
                _Pragma("unroll")                                             \
                for (int r = 0; r < 4; ++r) ssum[t][r] += fast_exp2(acc[r]);  \
            }                                                                 \
        } else {                                                              \
            const bool valid = ((v) * 16 + r16) < VOCAB;                      \
            _Pragma("unroll")                                                 \
            for (int t = 0; t < 8; ++t) {                                     \
                f32x4 acc = {0.f, 0.f, 0.f, 0.f};                             \
                acc = __builtin_amdgcn_mfma_f32_16x16x32_bf16(a[t][0], c0, acc, 0, 0, 0); \
                acc = __builtin_amdgcn_mfma_f32_16x16x32_bf16(a[t][1], c1, acc, 0, 0, 0); \
                _Pragma("unroll")                                             \
                for (int r = 0; r < 4; ++r) ssum[t][r] += valid ? fast_exp2(acc[r]) : 0.f; \
            }                                                                 \
        }                                                                     \
    } while (0)

    // incremental base pointer: row = vt*16 + r16, col offset hi*8
    const __bf16* p = Eb + ((size_t)vt * 16 + r16) * DIM + hi * 8;

    bf16x8 b0, b1, d0, d1;
    b0 = *(const bf16x8*)p;
    b1 = *(const bf16x8*)(p + 32);
    d0 = *(const bf16x8*)(p + 4096);              // +4 vtiles
    d1 = *(const bf16x8*)(p + 4096 + 32);

    while (vt < vt_end) {
        const bf16x8 c00 = b0, c01 = b1, c10 = d0, c11 = d1;
        const int v0 = vt, v1 = vt + 4;
        vt += 8;
        p += 8192;                                 // +8 vtiles
        b0 = *(const bf16x8*)p;
        b1 = *(const bf16x8*)(p + 32);
        d0 = *(const bf16x8*)(p + 4096);
        d1 = *(const bf16x8*)(p + 4096 + 32);

        DO_TILE(c00, c01, v0);
        if (v1 < vt_end) DO_TILE(c10, c11, v1);
    }
    #undef DO_TILE

    // reduce exp-sums across the 16 vocab cols (lanes differing in bits 0..3)
    #pragma unroll
    for (int t = 0; t < 8; ++t)
        #pragma unroll
        for (int r = 0; r < 4; ++r) {
            float v = ssum[t][r];
            v += __shfl_xor(v, 1);
            v += __shfl_xor(v, 2);
            v += __shfl_xor(v, 4);
            v += __shfl_xor(v, 8);
            ssum[t][r] = v;
        }

    if (r16 == 0) {
        const int slot = chunk * 4 + wslot;
        #pragma unroll
        for (int t = 0; t < 8; ++t)
            #pragma unroll
            for (int r = 0; r < 4; ++r) {
                const int row = bg * 128 + t * 16 + hi * 4 + r;
                partials[(size_t)slot * B_TOT + row] = ssum[t][r];
            }
    }
}

// ---------------------------------------------------------------------------
// Kernel C: reduce partials, exact fp32 pred logit, emit prob.
// ---------------------------------------------------------------------------
__global__ __launch_bounds__(256) void finalize_kernel(
    const float* __restrict__ Q,
    const float* __restrict__ item_emb,
    const int*   __restrict__ pred,
    const float* __restrict__ partials,
    float*       __restrict__ out)
{
    const int b = blockIdx.x * 256 + threadIdx.x;

    float S = 0.f;
    for (int w = 0; w < NC * 4; ++w)
        S += partials[(size_t)w * B_TOT + b];

    const int pv = pred[b];
    float acc = 0.f;
    const float4* e4 = (const float4*)(item_emb + (long)pv * DIM);
    const float4* q4 = (const float4*)(Q + b * DIM);
    #pragma unroll
    for (int i = 0; i < DIM / 4; ++i) {
        const float4 e = e4[i];
        const float4 q = q4[i];
        acc += e.x*q.x + e.y*q.y + e.z*q.z + e.w*q.w;
    }
    out[b] = __expf(acc) / S;
}

// ---------------------------------------------------------------------------
extern "C" void kernel_launch(void* const* d_in, const int* in_sizes, int n_in,
                              void* d_out, int out_size, void* d_ws, size_t ws_size,
                              hipStream_t stream)
{
    const int*   log_seqs = (const int*)  d_in[0];
    const int*   pred     = (const int*)  d_in[1];
    const float* item_emb = (const float*)d_in[2];
    const float* attn_key = (const float*)d_in[3];
    const float* pos_emb  = (const float*)d_in[4];
    float*       out      = (float*)d_out;

    char* ws = (char*)d_ws;
    const size_t eb_bytes = (size_t)(VOCAB + EB_SLACK_ROWS) * DIM * 2;  // + slack
    __bf16* Eb       = (__bf16*)ws;
    __bf16* Qb       = (__bf16*)(ws + eb_bytes);                        // 131,072 B
    float*  Qf       = (float*) (ws + eb_bytes + (size_t)B_TOT * DIM * 2);
    float*  partials = (float*) ((char*)Qf + (size_t)B_TOT * DIM * 4);  // [512][1024] f32

    pool_kernel<<<B_TOT, 256, 0, stream>>>(log_seqs, item_emb, attn_key, pos_emb, Qf, Qb, Eb);
    logits_mfma<<<NBG * NC * 4, 64, 0, stream>>>(Eb, Qb, partials);
    finalize_kernel<<<B_TOT / 256, 256, 0, stream>>>(Qf, item_emb, pred, partials, out);
}

// Round 16
// 63.975 us; speedup vs baseline: 1.2594x; 1.2594x over previous
//
#include <hip/hip_runtime.h>
#include <math.h>

#define B_TOT   1024
#define L_SEQ   200
#define DIM     64
#define VOCAB   100001
#define NEG_BIG (-1e15f)
#define SEQ_ST16 66                     // bf16 row stride: 132 B -> 2-way (free) on both write & read
#define LOG2E   1.4426950408889634f
#define EB_SLACK_ROWS 512               // stage overrun slack (values masked, never used)

typedef __bf16 bf16x8 __attribute__((ext_vector_type(8)));
typedef float  f32x4  __attribute__((ext_vector_type(4)));

// raw v_exp_f32 (exp2): inputs are bounded here, denormal guard unneeded
static __device__ __forceinline__ float fast_exp2(float x) {
    return __builtin_amdgcn_exp2f(x);
}

// ---------------------------------------------------------------------------
// Kernel A: attention pooling + tail-fused convert(E->bf16).  (R11 version)
// ---------------------------------------------------------------------------
__global__ __launch_bounds__(256) void pool_kernel(
    const int*   __restrict__ log_seqs,
    const float* __restrict__ item_emb,
    const float* __restrict__ attn_key,
    const float* __restrict__ pos_emb,
    float*       __restrict__ Q,
    __bf16*      __restrict__ Qb,
    __bf16*      __restrict__ Eb)
{
    const int b    = blockIdx.x;
    const int t    = threadIdx.x;
    const int wave = t >> 6;
    const int lane = t & 63;

    __shared__ unsigned short s_seq16[L_SEQ][SEQ_ST16];  // 26,400 B
    __shared__ float s_attn[L_SEQ];
    __shared__ float s_red[4];
    __shared__ float s_q[4][DIM];

    // ---- phase 1: seq row -> LDS (bf16), sim[l] ---------------------------
    float sim = -INFINITY;
    if (t < L_SEQ) {
        const int id = log_seqs[(long)b * L_SEQ + t];
        if (id == 0) {
            sim = NEG_BIG;
            const ushort2 z = make_ushort2(0, 0);
            #pragma unroll
            for (int i = 0; i < DIM / 2; ++i)
                *(ushort2*)&s_seq16[t][2 * i] = z;
        } else {
            float acc = 0.f;
            const float4* e4 = (const float4*)(item_emb + (long)id * DIM);
            const float4* p4 = (const float4*)(pos_emb + t * DIM);
            #pragma unroll
            for (int i = 0; i < DIM / 4; ++i) {
                const float4 e = e4[i];
                const float4 p = p4[i];
                float4 f;
                f.x = fmaf(8.f, e.x, p.x);
                f.y = fmaf(8.f, e.y, p.y);
                f.z = fmaf(8.f, e.z, p.z);
                f.w = fmaf(8.f, e.w, p.w);
                const __bf16 h0 = (__bf16)f.x, h1 = (__bf16)f.y;
                const __bf16 h2 = (__bf16)f.z, h3 = (__bf16)f.w;
                ushort2 u0, u1;
                u0.x = __builtin_bit_cast(unsigned short, h0);
                u0.y = __builtin_bit_cast(unsigned short, h1);
                u1.x = __builtin_bit_cast(unsigned short, h2);
                u1.y = __builtin_bit_cast(unsigned short, h3);
                *(ushort2*)&s_seq16[t][4 * i]     = u0;
                *(ushort2*)&s_seq16[t][4 * i + 2] = u1;
                // attn_key reads are thread-uniform -> scalar loads
                acc += f.x * attn_key[4*i+0] + f.y * attn_key[4*i+1]
                     + f.z * attn_key[4*i+2] + f.w * attn_key[4*i+3];
            }
            sim = acc;
        }
    }

    // ---- phase 2: block softmax over l -------------------------------------
    float m = sim;
    #pragma unroll
    for (int off = 32; off > 0; off >>= 1) m = fmaxf(m, __shfl_xor(m, off));
    if (lane == 0) s_red[wave] = m;
    __syncthreads();
    m = fmaxf(fmaxf(s_red[0], s_red[1]), fmaxf(s_red[2], s_red[3]));
    __syncthreads();                             // all waves read s_red

    float p = (t < L_SEQ) ? __expf(sim - m) : 0.f;
    if (t < L_SEQ) s_attn[t] = p;
    float ls = p;
    #pragma unroll
    for (int off = 32; off > 0; off >>= 1) ls += __shfl_xor(ls, off);
    if (lane == 0) s_red[wave] = ls;
    __syncthreads();
    const float inv = 1.0f / (s_red[0] + s_red[1] + s_red[2] + s_red[3]);

    // ---- phase 3: Q accumulation from LDS, L split across waves ------------
    float q = 0.f;
    const int l0 = wave * (L_SEQ / 4);
    #pragma unroll 2
    for (int l = l0; l < l0 + (L_SEQ / 4); ++l) {
        const unsigned int ui = (unsigned int)s_seq16[l][lane] << 16;
        q = fmaf(s_attn[l], __builtin_bit_cast(float, ui), q);
    }
    s_q[wave][lane] = q;
    __syncthreads();

    if (t < DIM) {
        const float qq = (s_q[0][t] + s_q[1][t] + s_q[2][t] + s_q[3][t]) * inv;
        Q[b * DIM + t]  = qq;
        Qb[b * DIM + t] = (__bf16)(qq * LOG2E);  // exp2-domain for logits kernel
    }

    // ---- tail: convert slice of item_emb -> bf16 ---------------------------
    {
        const long n8 = ((long)VOCAB * DIM) / 8;             // 800,008 groups
        for (long g = (long)b * 256 + t; g < n8; g += (long)gridDim.x * 256) {
            const long i = g * 8;
            const float4 f0 = ((const float4*)(item_emb + i))[0];
            const float4 f1 = ((const float4*)(item_emb + i))[1];
            bf16x8 o;
            o[0] = (__bf16)f0.x; o[1] = (__bf16)f0.y; o[2] = (__bf16)f0.z; o[3] = (__bf16)f0.w;
            o[4] = (__bf16)f1.x; o[5] = (__bf16)f1.y; o[6] = (__bf16)f1.z; o[7] = (__bf16)f1.w;
            *(bf16x8*)(Eb + i) = o;
        }
    }
}

// ---------------------------------------------------------------------------
// Kernel B: bf16 MFMA logits GEMM + exp2-sum partials.
// Block-cooperative staged structure (canonical GEMM shape):
//  - block = 4 waves, 128 batch rows; wave w owns b-tiles {2w, 2w+1}
//    -> a[2][2] (16 VGPR), ssum[2][4] (8)  => ~70 VGPR, 8 waves/SIMD allowed
//  - per phase, 8 vtiles (16 KB) staged LDS cooperatively (coalesced 16B/lane),
//    XOR-swizzled slot ^= (row&7)<<4 (else fragment read = 16-way conflict);
//    all 4 waves consume every staged vtile -> 16 MFMAs per global fetch
//  - single buffer + 2 barriers (m97: inter-block overlap at 8 blocks/CU
//    hides the drain); NC=256 -> grid 2048 = 8 blocks/CU
//  - stage overrun lands in Eb slack; tail vtile masks valid?:0 (B row r16
//    only feeds col r16 -> garbage confined to masked lanes)
//  - waves own disjoint rows -> no cross-wave reduce
// XCD decode: chunk == xcd (mod 8); L2-resident chunk working set.
// ---------------------------------------------------------------------------
#define NC        256                   // vocab chunks
#define NBG       8                     // batch groups (1024/128)
#define VT_TOTAL  6251                  // ceil(100001/16)
#define VT_FULL   6250
#define VT_PER    25                    // ceil(VT_TOTAL/NC)
#define STAGE_VT  8                     // vtiles per stage phase (16 KB)

__global__ __launch_bounds__(256) void logits_mfma(
    const __bf16* __restrict__ Eb,      // [VOCAB+slack][64]
    const __bf16* __restrict__ Qb,      // [1024][64], exp2-domain
    float*        __restrict__ partials) // [NC][1024]
{
    const int bid   = blockIdx.x;                 // 0..2047
    const int xcd   = bid & 7;          // HW round-robins blockIdx across XCDs
    const int idx   = bid >> 3;         // 0..255 within this XCD
    const int chunk = xcd + 8 * (idx >> 3);       // chunks == xcd (mod 8)
    const int bg    = idx & 7;
    const int tid   = threadIdx.x;
    const int wave  = tid >> 6;
    const int lane  = tid & 63;
    const int r16   = lane & 15;
    const int hi    = lane >> 4;

    __shared__ char s_stage[STAGE_VT * 2048];     // 16,384 B

    bf16x8 a[2][2];
    #pragma unroll
    for (int t = 0; t < 2; ++t)
        #pragma unroll
        for (int s = 0; s < 2; ++s)
            a[t][s] = *(const bf16x8*)(Qb + ((bg*128 + (wave*2 + t)*16 + r16) * DIM) + s*32 + hi*8);

    const int vt0    = chunk * VT_PER;
    const int vt_end = min(vt0 + VT_PER, VT_TOTAL);
    const int nvt    = vt_end - vt0;
    const int nphase = nvt > 0 ? (nvt + STAGE_VT - 1) / STAGE_VT : 0;

    float ssum[2][4];
    #pragma unroll
    for (int t = 0; t < 2; ++t)
        #pragma unroll
        for (int r = 0; r < 4; ++r) ssum[t][r] = 0.f;

    // swizzled read offsets for this lane's fragment (within a 2 KB vtile)
    const int rbase = r16 * 128;
    const int x0 = (hi * 16)        ^ ((r16 & 7) << 4);
    const int x1 = ((hi * 16) + 64) ^ ((r16 & 7) << 4);

    for (int ph = 0; ph < nphase; ++ph) {
        const int vtg0 = vt0 + ph * STAGE_VT;
        __syncthreads();                          // prev compute done before overwrite
        {   // stage 8 vtiles = 128 rows x 64 cols bf16, coalesced, swizzled
            const __bf16* src = Eb + (size_t)vtg0 * 16 * DIM;
            bf16x8 v[4];
            #pragma unroll
            for (int k = 0; k < 4; ++k) {
                const int g = k * 256 + tid;      // 0..1023
                v[k] = *(const bf16x8*)(src + (size_t)(g >> 3) * DIM + (g & 7) * 8);
            }
            #pragma unroll
            for (int k = 0; k < 4; ++k) {
                const int g    = k * 256 + tid;
                const int rowg = g >> 3;          // 0..127
                const int slot = g & 7;
                const int row  = rowg & 15;
                const int vl   = rowg >> 4;
                const int db   = vl * 2048 + row * 128 + ((slot * 16) ^ ((row & 7) << 4));
                *(bf16x8*)(s_stage + db) = v[k];
            }
        }
        __syncthreads();                          // staged data visible

        const int nv = min(STAGE_VT, vt_end - vtg0);
        for (int vl = 0; vl < nv; ++vl) {
            const char* vb = s_stage + vl * 2048 + rbase;
            const bf16x8 c0 = *(const bf16x8*)(vb + x0);
            const bf16x8 c1 = *(const bf16x8*)(vb + x1);
            const int vt_g = vtg0 + vl;
            if (vt_g < VT_FULL) {
                #pragma unroll
                for (int t = 0; t < 2; ++t) {
                    f32x4 acc = {0.f, 0.f, 0.f, 0.f};
                    acc = __builtin_amdgcn_mfma_f32_16x16x32_bf16(a[t][0], c0, acc, 0, 0, 0);
                    acc = __builtin_amdgcn_mfma_f32_16x16x32_bf16(a[t][1], c1, acc, 0, 0, 0);
                    #pragma unroll
                    for (int r = 0; r < 4; ++r) ssum[t][r] += fast_exp2(acc[r]);
                }
            } else {
                const bool valid = (vt_g * 16 + r16) < VOCAB;
                #pragma unroll
                for (int t = 0; t < 2; ++t) {
                    f32x4 acc = {0.f, 0.f, 0.f, 0.f};
                    acc = __builtin_amdgcn_mfma_f32_16x16x32_bf16(a[t][0], c0, acc, 0, 0, 0);
                    acc = __builtin_amdgcn_mfma_f32_16x16x32_bf16(a[t][1], c1, acc, 0, 0, 0);
                    #pragma unroll
                    for (int r = 0; r < 4; ++r) ssum[t][r] += valid ? fast_exp2(acc[r]) : 0.f;
                }
            }
        }
    }

    // reduce exp-sums across the 16 vocab cols (lanes differing in bits 0..3)
    #pragma unroll
    for (int t = 0; t < 2; ++t)
        #pragma unroll
        for (int r = 0; r < 4; ++r) {
            float v = ssum[t][r];
            v += __shfl_xor(v, 1);
            v += __shfl_xor(v, 2);
            v += __shfl_xor(v, 4);
            v += __shfl_xor(v, 8);
            ssum[t][r] = v;
        }

    // waves own disjoint rows -> direct write, no cross-wave reduce
    if (r16 == 0) {
        #pragma unroll
        for (int t = 0; t < 2; ++t)
            #pragma unroll
            for (int r = 0; r < 4; ++r) {
                const int row = bg * 128 + (wave*2 + t) * 16 + hi * 4 + r;
                partials[(size_t)chunk * B_TOT + row] = ssum[t][r];
            }
    }
}

// ---------------------------------------------------------------------------
// Kernel C: reduce partials, exact fp32 pred logit, emit prob.
// ---------------------------------------------------------------------------
__global__ __launch_bounds__(256) void finalize_kernel(
    const float* __restrict__ Q,
    const float* __restrict__ item_emb,
    const int*   __restrict__ pred,
    const float* __restrict__ partials,
    float*       __restrict__ out)
{
    const int b = blockIdx.x * 256 + threadIdx.x;

    float S = 0.f;
    for (int c = 0; c < NC; ++c)
        S += partials[(size_t)c * B_TOT + b];

    const int pv = pred[b];
    float acc = 0.f;
    const float4* e4 = (const float4*)(item_emb + (long)pv * DIM);
    const float4* q4 = (const float4*)(Q + b * DIM);
    #pragma unroll
    for (int i = 0; i < DIM / 4; ++i) {
        const float4 e = e4[i];
        const float4 q = q4[i];
        acc += e.x*q.x + e.y*q.y + e.z*q.z + e.w*q.w;
    }
    out[b] = __expf(acc) / S;
}

// ---------------------------------------------------------------------------
extern "C" void kernel_launch(void* const* d_in, const int* in_sizes, int n_in,
                              void* d_out, int out_size, void* d_ws, size_t ws_size,
                              hipStream_t stream)
{
    const int*   log_seqs = (const int*)  d_in[0];
    const int*   pred     = (const int*)  d_in[1];
    const float* item_emb = (const float*)d_in[2];
    const float* attn_key = (const float*)d_in[3];
    const float* pos_emb  = (const float*)d_in[4];
    float*       out      = (float*)d_out;

    char* ws = (char*)d_ws;
    const size_t eb_bytes = (size_t)(VOCAB + EB_SLACK_ROWS) * DIM * 2;  // + slack
    __bf16* Eb       = (__bf16*)ws;
    __bf16* Qb       = (__bf16*)(ws + eb_bytes);                        // 131,072 B
    float*  Qf       = (float*) (ws + eb_bytes + (size_t)B_TOT * DIM * 2);
    float*  partials = (float*) ((char*)Qf + (size_t)B_TOT * DIM * 4);  // [256][1024] f32

    pool_kernel<<<B_TOT, 256, 0, stream>>>(log_seqs, item_emb, attn_key, pos_emb, Qf, Qb, Eb);
    logits_mfma<<<NBG * NC, 256, 0, stream>>>(Eb, Qb, partials);
    finalize_kernel<<<B_TOT / 256, 256, 0, stream>>>(Qf, item_emb, pred, partials, out);
}